// Round 1
// baseline (281.864 us; speedup 1.0000x reference)
//
#include <hip/hip_runtime.h>

// Problem constants (fixed by the reference module)
#define IMG_H 1024
#define IMG_W 1024
#define NPIX (IMG_H * IMG_W)
#define N_MASKS 32
#define N_WINDOWS 4
#define MPW 8          // N_MASKS / N_WINDOWS
#define WIN_H 512
#define WIN_W 512
#define SIM_THRESH 0.1f

// Workspace layout
#define WS_EDGE 0      // 4 x uint32 edge masks: [0]=left [1]=right [2]=top [3]=bottom
#define WS_LOC  64     // 32 x int32 channel remap
#define WS_IDS  256    // NPIX bytes of per-pixel argmax ids

__global__ void k_init(unsigned* e) {
    if (threadIdx.x < 4) e[threadIdx.x] = 0u;
}

// Pass 1: per-pixel argmax over 32 channels (4 pixels/thread, float4 loads),
// store ids to ws, atomicOr edge-channel bits for window-border pixels.
template <bool STORE_IDS>
__global__ __launch_bounds__(256) void k_argmax(const float* __restrict__ masks,
                                                const int* __restrict__ pl,
                                                const int* __restrict__ pt,
                                                unsigned* __restrict__ edge_masks,
                                                unsigned char* __restrict__ ids) {
    __shared__ int spl[4], spt[4];
    if (threadIdx.x < 4) { spl[threadIdx.x] = pl[threadIdx.x]; spt[threadIdx.x] = pt[threadIdx.x]; }
    __syncthreads();

    int t = blockIdx.x * blockDim.x + threadIdx.x;
    int idx = t * 4;
    if (idx >= NPIX) return;

    float bv[4];
    int bc[4];
    {
        const float4 v = *(const float4*)(masks + idx);
        bv[0] = v.x; bv[1] = v.y; bv[2] = v.z; bv[3] = v.w;
        bc[0] = bc[1] = bc[2] = bc[3] = 0;
    }
#pragma unroll
    for (int c = 1; c < N_MASKS; c++) {
        const float4 v = *(const float4*)(masks + (size_t)c * NPIX + idx);
        if (v.x > bv[0]) { bv[0] = v.x; bc[0] = c; }
        if (v.y > bv[1]) { bv[1] = v.y; bc[1] = c; }
        if (v.z > bv[2]) { bv[2] = v.z; bc[2] = c; }
        if (v.w > bv[3]) { bv[3] = v.w; bc[3] = c; }
    }

    if (STORE_IDS) {
        uchar4 o;
        o.x = (unsigned char)bc[0]; o.y = (unsigned char)bc[1];
        o.z = (unsigned char)bc[2]; o.w = (unsigned char)bc[3];
        *(uchar4*)(ids + idx) = o;
    }

    // Edge flags: only channels belonging to window wi, only within wi's region.
    int y = idx >> 10;
    int x0 = idx & (IMG_W - 1);
#pragma unroll
    for (int wi = 0; wi < N_WINDOWS; wi++) {
        int xs = max(spl[wi], 0), xe = min(spl[wi] + WIN_W, IMG_W);
        int ys = max(spt[wi], 0), ye = min(spt[wi] + WIN_H, IMG_H);
        if (ys >= ye || xs >= xe) continue;
        if (y < ys || y >= ye) continue;
#pragma unroll
        for (int k = 0; k < 4; k++) {
            int x = x0 + k;
            if (x < xs || x >= xe) continue;
            int c = bc[k];
            if ((c >> 3) != wi) continue;  // c in [wi*MPW, (wi+1)*MPW)
            unsigned bit = 1u << c;
            if (x == xs)     atomicOr(&edge_masks[0], bit);
            if (x == xe - 1) atomicOr(&edge_masks[1], bit);
            if (y == ys)     atomicOr(&edge_masks[2], bit);
            if (y == ye - 1) atomicOr(&edge_masks[3], bit);
        }
    }
}

// Pass 2: one wave. Normalize slot features, build adjacency + pair list in
// reference order, compute sims, run the sequential merge scan -> loc[32].
__global__ __launch_bounds__(64) void k_merge(const float* __restrict__ sf,
                                              const int* __restrict__ pl,
                                              const int* __restrict__ pt,
                                              const unsigned* __restrict__ edge_masks,
                                              int* __restrict__ loc_out) {
    __shared__ float sfn[N_WINDOWS * (MPW - 1) * 64];   // 28 rows x 64
    __shared__ unsigned char pci[640], pcj[640], phz[640], pass_[640];
    __shared__ int sP;
    int lane = threadIdx.x;

    // Normalize each (window, slot) feature row: x / (||x|| + 1e-8)
    for (int r = 0; r < N_WINDOWS * (MPW - 1); r++) {
        float v = sf[r * 64 + lane];
        float s = v * v;
#pragma unroll
        for (int off = 1; off < 64; off <<= 1) s += __shfl_xor(s, off, 64);
        sfn[r * 64 + lane] = v * (1.0f / (sqrtf(s) + 1e-8f));
    }
    __syncthreads();

    if (lane == 0) {
        int lpl[4], lpt[4];
        for (int i = 0; i < 4; i++) { lpl[i] = pl[i]; lpt[i] = pt[i]; }
        int aI[12], aJ[12], aH[12], na = 0;
        for (int i = 0; i < N_WINDOWS; i++)
            for (int j = i + 1; j < N_WINDOWS; j++) {
                if (lpt[i] == lpt[j] && abs(lpl[i] - lpl[j]) == WIN_W) {
                    if (lpl[i] < lpl[j]) { aI[na] = i; aJ[na] = j; }
                    else                 { aI[na] = j; aJ[na] = i; }
                    aH[na] = 1; na++;
                }
                if (lpl[i] == lpl[j] && abs(lpt[i] - lpt[j]) == WIN_H) {
                    if (lpt[i] < lpt[j]) { aI[na] = i; aJ[na] = j; }
                    else                 { aI[na] = j; aJ[na] = i; }
                    aH[na] = 0; na++;
                }
            }
        int P = 0;
        for (int a = 0; a < na; a++)
            for (int ci = aI[a] * MPW + 1; ci < (aI[a] + 1) * MPW; ci++)
                for (int cj = aJ[a] * MPW + 1; cj < (aJ[a] + 1) * MPW; cj++) {
                    pci[P] = (unsigned char)ci;
                    pcj[P] = (unsigned char)cj;
                    phz[P] = (unsigned char)aH[a];
                    P++;
                }
        sP = P;
    }
    __syncthreads();

    int P = sP;
    unsigned el = edge_masks[0], er = edge_masks[1], et = edge_masks[2], eb = edge_masks[3];
    for (int p = lane; p < P; p += 64) {
        int ci = pci[p], cj = pcj[p];
        int wi = ci >> 3, wj = cj >> 3;
        const float* fi = &sfn[(wi * (MPW - 1) + (ci & 7) - 1) * 64];
        const float* fj = &sfn[(wj * (MPW - 1) + (cj & 7) - 1) * 64];
        float s = 0.f;
#pragma unroll
        for (int k = 0; k < 64; k++) s += fi[k] * fj[k];
        bool eok = phz[p] ? (((er >> ci) & 1u) && ((el >> cj) & 1u))
                          : (((eb >> ci) & 1u) && ((et >> cj) & 1u));
        pass_[p] = (eok && s > SIM_THRESH) ? 1 : 0;
    }
    __syncthreads();

    if (lane == 0) {
        int loc[32];
        unsigned merged = 0;
        for (int c = 0; c < 32; c++) loc[c] = c;
        for (int p = 0; p < P; p++) {
            int ci = pci[p], cj = pcj[p];
            if (pass_[p] && !((merged >> ci) & 1u) && !((merged >> cj) & 1u)) {
                int keep = min(ci, cj), rem = max(ci, cj);
                for (int o = 0; o < 32; o++)
                    if (loc[o] == rem) loc[o] = keep;
                merged |= 1u << rem;
            }
        }
        for (int c = 0; c < 32; c++) loc_out[c] = loc[c];
    }
}

// Pass 3: out[c][p] = (loc[ids[p]] == c). 4 pixels/thread, float4 stores.
__global__ __launch_bounds__(256) void k_write(const unsigned char* __restrict__ ids,
                                               const int* __restrict__ loc_g,
                                               float* __restrict__ out) {
    __shared__ int loc[32];
    if (threadIdx.x < 32) loc[threadIdx.x] = loc_g[threadIdx.x];
    __syncthreads();

    int t = blockIdx.x * blockDim.x + threadIdx.x;
    int idx = t * 4;
    if (idx >= NPIX) return;

    uchar4 id4 = *(const uchar4*)(ids + idx);
    int r0 = loc[id4.x], r1 = loc[id4.y], r2 = loc[id4.z], r3 = loc[id4.w];
#pragma unroll
    for (int c = 0; c < N_MASKS; c++) {
        float4 v;
        v.x = (r0 == c) ? 1.0f : 0.0f;
        v.y = (r1 == c) ? 1.0f : 0.0f;
        v.z = (r2 == c) ? 1.0f : 0.0f;
        v.w = (r3 == c) ? 1.0f : 0.0f;
        *(float4*)(out + (size_t)c * NPIX + idx) = v;
    }
}

// Fallback pass 3 if ws can't hold the ids array: recompute argmax from masks.
__global__ __launch_bounds__(256) void k_write_recompute(const float* __restrict__ masks,
                                                         const int* __restrict__ loc_g,
                                                         float* __restrict__ out) {
    __shared__ int loc[32];
    if (threadIdx.x < 32) loc[threadIdx.x] = loc_g[threadIdx.x];
    __syncthreads();

    int t = blockIdx.x * blockDim.x + threadIdx.x;
    int idx = t * 4;
    if (idx >= NPIX) return;

    float bv[4];
    int bc[4];
    {
        const float4 v = *(const float4*)(masks + idx);
        bv[0] = v.x; bv[1] = v.y; bv[2] = v.z; bv[3] = v.w;
        bc[0] = bc[1] = bc[2] = bc[3] = 0;
    }
#pragma unroll
    for (int c = 1; c < N_MASKS; c++) {
        const float4 v = *(const float4*)(masks + (size_t)c * NPIX + idx);
        if (v.x > bv[0]) { bv[0] = v.x; bc[0] = c; }
        if (v.y > bv[1]) { bv[1] = v.y; bc[1] = c; }
        if (v.z > bv[2]) { bv[2] = v.z; bc[2] = c; }
        if (v.w > bv[3]) { bv[3] = v.w; bc[3] = c; }
    }
    int r0 = loc[bc[0]], r1 = loc[bc[1]], r2 = loc[bc[2]], r3 = loc[bc[3]];
#pragma unroll
    for (int c = 0; c < N_MASKS; c++) {
        float4 v;
        v.x = (r0 == c) ? 1.0f : 0.0f;
        v.y = (r1 == c) ? 1.0f : 0.0f;
        v.z = (r2 == c) ? 1.0f : 0.0f;
        v.w = (r3 == c) ? 1.0f : 0.0f;
        *(float4*)(out + (size_t)c * NPIX + idx) = v;
    }
}

extern "C" void kernel_launch(void* const* d_in, const int* in_sizes, int n_in,
                              void* d_out, int out_size, void* d_ws, size_t ws_size,
                              hipStream_t stream) {
    const float* masks = (const float*)d_in[0];       // (1, 32, 1024, 1024) f32
    const float* sf    = (const float*)d_in[1];       // (4, 7, 64) f32
    const int*   pl    = (const int*)d_in[2];         // (4,) i32
    const int*   pt    = (const int*)d_in[3];         // (4,) i32
    float* out = (float*)d_out;

    char* ws = (char*)d_ws;
    unsigned* edge_masks = (unsigned*)(ws + WS_EDGE);
    int* loc = (int*)(ws + WS_LOC);
    unsigned char* ids = (unsigned char*)(ws + WS_IDS);

    const bool have_ids_ws = (ws_size >= (size_t)(WS_IDS + NPIX));

    const int nthreads = NPIX / 4;           // 4 pixels per thread
    const int blocks = nthreads / 256;       // 1024 blocks

    k_init<<<1, 64, 0, stream>>>(edge_masks);

    if (have_ids_ws) {
        k_argmax<true><<<blocks, 256, 0, stream>>>(masks, pl, pt, edge_masks, ids);
        k_merge<<<1, 64, 0, stream>>>(sf, pl, pt, edge_masks, loc);
        k_write<<<blocks, 256, 0, stream>>>(ids, loc, out);
    } else {
        k_argmax<false><<<blocks, 256, 0, stream>>>(masks, pl, pt, edge_masks, nullptr);
        k_merge<<<1, 64, 0, stream>>>(sf, pl, pt, edge_masks, loc);
        k_write_recompute<<<blocks, 256, 0, stream>>>(masks, loc, out);
    }
}

// Round 3
// 275.506 us; speedup vs baseline: 1.0231x; 1.0231x over previous
//
#include <hip/hip_runtime.h>

// Problem constants (fixed by the reference module)
#define IMG_H 1024
#define IMG_W 1024
#define NPIX (IMG_H * IMG_W)
#define N_MASKS 32
#define N_WINDOWS 4
#define MPW 8          // N_MASKS / N_WINDOWS
#define WIN_H 512
#define WIN_W 512
#define SIM_THRESH 0.1f
#define NBLK 1024      // grid for the two streaming kernels (block == one image row)

// Native 4-float vector for __builtin_nontemporal_store (HIP float4 is a class)
typedef float vf4 __attribute__((ext_vector_type(4)));

// Workspace layout (bytes)
#define WS_LOC   0                      // 32 x int32 channel remap
#define WS_EDGE  128                    // NBLK x uint4 per-block edge masks (l,r,t,b)
#define WS_IDS   (WS_EDGE + NBLK * 16)  // NPIX bytes of per-pixel argmax ids

// Pass 1: per-pixel argmax over 32 channels (4 px/thread, float4 loads).
// Edge-channel bits aggregated per block in LDS, one uint4 store per block —
// no global atomics, no init kernel needed.
__global__ __launch_bounds__(256) void k_argmax(const float* __restrict__ masks,
                                                const int* __restrict__ pl,
                                                const int* __restrict__ pt,
                                                uint4* __restrict__ edge_blocks,
                                                unsigned char* __restrict__ ids) {
    __shared__ int spl[4], spt[4];
    __shared__ unsigned sem[4];
    const int tid = threadIdx.x;
    if (tid < 4) { spl[tid] = pl[tid]; spt[tid] = pt[tid]; sem[tid] = 0u; }
    __syncthreads();

    const int idx = (blockIdx.x * 256 + tid) * 4;   // exact fit: no guard needed

    float bv0, bv1, bv2, bv3;
    int bc0 = 0, bc1 = 0, bc2 = 0, bc3 = 0;
    {
        const float4 v = *(const float4*)(masks + idx);
        bv0 = v.x; bv1 = v.y; bv2 = v.z; bv3 = v.w;
    }
#pragma unroll
    for (int c = 1; c < N_MASKS; c++) {
        const float4 v = *(const float4*)(masks + (size_t)c * NPIX + idx);
        if (v.x > bv0) { bv0 = v.x; bc0 = c; }
        if (v.y > bv1) { bv1 = v.y; bc1 = c; }
        if (v.z > bv2) { bv2 = v.z; bc2 = c; }
        if (v.w > bv3) { bv3 = v.w; bc3 = c; }
    }
    *(uchar4*)(ids + idx) = make_uchar4((unsigned char)bc0, (unsigned char)bc1,
                                        (unsigned char)bc2, (unsigned char)bc3);

    const int y = idx >> 10;
    const int x0 = idx & (IMG_W - 1);
    const int bcs[4] = {bc0, bc1, bc2, bc3};
#pragma unroll
    for (int wi = 0; wi < N_WINDOWS; wi++) {
        const int xs = max(spl[wi], 0), xe = min(spl[wi] + WIN_W, IMG_W);
        const int ys = max(spt[wi], 0), ye = min(spt[wi] + WIN_H, IMG_H);
        if (ys >= ye || xs >= xe) continue;
        if (y < ys || y >= ye) continue;
#pragma unroll
        for (int k = 0; k < 4; k++) {
            const int x = x0 + k;
            if (x < xs || x >= xe) continue;
            const int c = bcs[k];
            if ((c >> 3) != wi) continue;   // channel must belong to window wi
            const unsigned bit = 1u << c;
            if (x == xs)     atomicOr(&sem[0], bit);   // LDS atomic, rare
            if (x == xe - 1) atomicOr(&sem[1], bit);
            if (y == ys)     atomicOr(&sem[2], bit);
            if (y == ye - 1) atomicOr(&sem[3], bit);
        }
    }
    __syncthreads();
    if (tid == 0) edge_blocks[blockIdx.x] = make_uint4(sem[0], sem[1], sem[2], sem[3]);
}

// Pass 2: one wave. OR-reduce block edge masks, normalize slot features,
// build the pair list in reference order, compute sims, run the merge scan
// with lane-parallel loc update.
__global__ __launch_bounds__(64) void k_merge(const float* __restrict__ sf,
                                              const int* __restrict__ pl,
                                              const int* __restrict__ pt,
                                              const uint4* __restrict__ edge_blocks,
                                              int* __restrict__ loc_out) {
    __shared__ float sfn[28 * 65];          // stride-65 pad kills bank conflicts
    __shared__ unsigned step_word[512];     // ci | cj<<8 | hz<<16 | pass<<17
    __shared__ int sP;
    const int lane = threadIdx.x;

    // 1) reduce per-block edge masks
    unsigned el = 0, er = 0, et = 0, eb = 0;
    for (int b = lane; b < NBLK; b += 64) {
        const uint4 w = edge_blocks[b];
        el |= w.x; er |= w.y; et |= w.z; eb |= w.w;
    }
#pragma unroll
    for (int off = 1; off < 64; off <<= 1) {
        el |= __shfl_xor(el, off);
        er |= __shfl_xor(er, off);
        et |= __shfl_xor(et, off);
        eb |= __shfl_xor(eb, off);
    }

    // 2) normalize slot features: x / (||x|| + 1e-8)
    for (int r = 0; r < N_WINDOWS * (MPW - 1); r++) {
        const float v = sf[r * 64 + lane];
        float s = v * v;
#pragma unroll
        for (int off = 1; off < 64; off <<= 1) s += __shfl_xor(s, off);
        sfn[r * 65 + lane] = v * (1.0f / (sqrtf(s) + 1e-8f));
    }

    // 3) adjacency + pair list in reference order (lane 0)
    if (lane == 0) {
        int lpl[4], lpt[4];
        for (int i = 0; i < 4; i++) { lpl[i] = pl[i]; lpt[i] = pt[i]; }
        int aI[8], aJ[8], aH[8], na = 0;
        for (int i = 0; i < N_WINDOWS; i++)
            for (int j = i + 1; j < N_WINDOWS; j++) {
                if (lpt[i] == lpt[j] && abs(lpl[i] - lpl[j]) == WIN_W) {
                    if (lpl[i] < lpl[j]) { aI[na] = i; aJ[na] = j; }
                    else                 { aI[na] = j; aJ[na] = i; }
                    aH[na] = 1; na++;
                }
                if (lpl[i] == lpl[j] && abs(lpt[i] - lpt[j]) == WIN_H) {
                    if (lpt[i] < lpt[j]) { aI[na] = i; aJ[na] = j; }
                    else                 { aI[na] = j; aJ[na] = i; }
                    aH[na] = 0; na++;
                }
            }
        int P = 0;
        for (int a = 0; a < na; a++)
            for (int ci = aI[a] * MPW + 1; ci < (aI[a] + 1) * MPW; ci++)
                for (int cj = aJ[a] * MPW + 1; cj < (aJ[a] + 1) * MPW; cj++)
                    step_word[P++] = (unsigned)ci | ((unsigned)cj << 8)
                                   | ((unsigned)aH[a] << 16);
        sP = P;
    }
    __syncthreads();

    // 4) sims + pass bit
    const int P = sP;
    for (int p = lane; p < P; p += 64) {
        const unsigned w = step_word[p];
        const int ci = w & 255, cj = (w >> 8) & 255, hz = (w >> 16) & 1;
        const float* fi = &sfn[((ci >> 3) * (MPW - 1) + (ci & 7) - 1) * 65];
        const float* fj = &sfn[((cj >> 3) * (MPW - 1) + (cj & 7) - 1) * 65];
        float s = 0.f;
#pragma unroll
        for (int k = 0; k < 64; k++) s += fi[k] * fj[k];
        const bool eok = hz ? (((er >> ci) & 1u) && ((el >> cj) & 1u))
                            : (((eb >> ci) & 1u) && ((et >> cj) & 1u));
        if (eok && s > SIM_THRESH) step_word[p] = w | (1u << 17);
    }
    __syncthreads();

    // 5) sequential scan, lane-parallel loc update (lane c carries loc[c])
    unsigned merged = 0;
    int myloc = lane;
    for (int p = 0; p < P; p++) {
        const unsigned w = step_word[p];            // LDS broadcast
        if (w >> 17) {
            const int ci = w & 255, cj = (w >> 8) & 255;
            if (!((merged >> ci) & 1u) && !((merged >> cj) & 1u)) {
                const int keep = min(ci, cj), rem = max(ci, cj);
                if (myloc == rem) myloc = keep;
                merged |= 1u << rem;
            }
        }
    }
    if (lane < 32) loc_out[lane] = myloc;
}

// Pass 3: out[c][p] = (loc[ids[p]] == c). 4 px/thread, nontemporal float4 stores.
__global__ __launch_bounds__(256) void k_write(const unsigned char* __restrict__ ids,
                                               const int* __restrict__ loc_g,
                                               float* __restrict__ out) {
    __shared__ int loc[32];
    if (threadIdx.x < 32) loc[threadIdx.x] = loc_g[threadIdx.x];
    __syncthreads();

    const int idx = (blockIdx.x * 256 + threadIdx.x) * 4;   // exact fit
    const uchar4 id4 = *(const uchar4*)(ids + idx);
    const int r0 = loc[id4.x], r1 = loc[id4.y], r2 = loc[id4.z], r3 = loc[id4.w];
#pragma unroll
    for (int c = 0; c < N_MASKS; c++) {
        vf4 v;
        v.x = (r0 == c) ? 1.0f : 0.0f;
        v.y = (r1 == c) ? 1.0f : 0.0f;
        v.z = (r2 == c) ? 1.0f : 0.0f;
        v.w = (r3 == c) ? 1.0f : 0.0f;
        __builtin_nontemporal_store(v, (vf4*)(out + (size_t)c * NPIX + idx));
    }
}

extern "C" void kernel_launch(void* const* d_in, const int* in_sizes, int n_in,
                              void* d_out, int out_size, void* d_ws, size_t ws_size,
                              hipStream_t stream) {
    const float* masks = (const float*)d_in[0];   // (1, 32, 1024, 1024) f32
    const float* sf    = (const float*)d_in[1];   // (4, 7, 64) f32
    const int*   pl    = (const int*)d_in[2];     // (4,) i32
    const int*   pt    = (const int*)d_in[3];     // (4,) i32
    float* out = (float*)d_out;

    char* ws = (char*)d_ws;
    int* loc = (int*)(ws + WS_LOC);
    uint4* edge_blocks = (uint4*)(ws + WS_EDGE);
    unsigned char* ids = (unsigned char*)(ws + WS_IDS);

    k_argmax<<<NBLK, 256, 0, stream>>>(masks, pl, pt, edge_blocks, ids);
    k_merge<<<1, 64, 0, stream>>>(sf, pl, pt, edge_blocks, loc);
    k_write<<<NBLK, 256, 0, stream>>>(ids, loc, out);
}

// Round 4
// 262.211 us; speedup vs baseline: 1.0750x; 1.0507x over previous
//
#include <hip/hip_runtime.h>

// Problem constants (fixed by the reference module)
#define IMG_H 1024
#define IMG_W 1024
#define NPIX (IMG_H * IMG_W)
#define N_MASKS 32
#define N_WINDOWS 4
#define MPW 8          // N_MASKS / N_WINDOWS
#define WIN_H 512
#define WIN_W 512
#define SIM_THRESH 0.1f
#define NBLK 1024      // grid for the two streaming kernels (block == one image row)

// Native 4-float vector for __builtin_nontemporal_store (HIP float4 is a class)
typedef float vf4 __attribute__((ext_vector_type(4)));

// Workspace layout (bytes)
#define WS_EDGE  0                      // NBLK x uint4 per-block edge masks (l,r,t,b)
#define WS_IDS   (NBLK * 16)            // NPIX bytes of per-pixel argmax ids

// Pass 1: per-pixel argmax over 32 channels (4 px/thread, float4 loads).
// Edge-channel bits aggregated per block in LDS, one uint4 store per block.
__global__ __launch_bounds__(256) void k_argmax(const float* __restrict__ masks,
                                                const int* __restrict__ pl,
                                                const int* __restrict__ pt,
                                                uint4* __restrict__ edge_blocks,
                                                unsigned char* __restrict__ ids) {
    __shared__ int spl[4], spt[4];
    __shared__ unsigned sem[4];
    const int tid = threadIdx.x;
    if (tid < 4) { spl[tid] = pl[tid]; spt[tid] = pt[tid]; sem[tid] = 0u; }
    __syncthreads();

    const int idx = (blockIdx.x * 256 + tid) * 4;   // exact fit: no guard needed

    float bv0, bv1, bv2, bv3;
    int bc0 = 0, bc1 = 0, bc2 = 0, bc3 = 0;
    {
        const float4 v = *(const float4*)(masks + idx);
        bv0 = v.x; bv1 = v.y; bv2 = v.z; bv3 = v.w;
    }
#pragma unroll
    for (int c = 1; c < N_MASKS; c++) {
        const float4 v = *(const float4*)(masks + (size_t)c * NPIX + idx);
        if (v.x > bv0) { bv0 = v.x; bc0 = c; }
        if (v.y > bv1) { bv1 = v.y; bc1 = c; }
        if (v.z > bv2) { bv2 = v.z; bc2 = c; }
        if (v.w > bv3) { bv3 = v.w; bc3 = c; }
    }
    *(uchar4*)(ids + idx) = make_uchar4((unsigned char)bc0, (unsigned char)bc1,
                                        (unsigned char)bc2, (unsigned char)bc3);

    const int y = idx >> 10;
    const int x0 = idx & (IMG_W - 1);
    const int bcs[4] = {bc0, bc1, bc2, bc3};
#pragma unroll
    for (int wi = 0; wi < N_WINDOWS; wi++) {
        const int xs = max(spl[wi], 0), xe = min(spl[wi] + WIN_W, IMG_W);
        const int ys = max(spt[wi], 0), ye = min(spt[wi] + WIN_H, IMG_H);
        if (ys >= ye || xs >= xe) continue;
        if (y < ys || y >= ye) continue;
#pragma unroll
        for (int k = 0; k < 4; k++) {
            const int x = x0 + k;
            if (x < xs || x >= xe) continue;
            const int c = bcs[k];
            if ((c >> 3) != wi) continue;   // channel must belong to window wi
            const unsigned bit = 1u << c;
            if (x == xs)     atomicOr(&sem[0], bit);   // LDS atomic, rare
            if (x == xe - 1) atomicOr(&sem[1], bit);
            if (y == ys)     atomicOr(&sem[2], bit);
            if (y == ye - 1) atomicOr(&sem[3], bit);
        }
    }
    __syncthreads();
    if (tid == 0) edge_blocks[blockIdx.x] = make_uint4(sem[0], sem[1], sem[2], sem[3]);
}

// Pass 2 (fused): every block redundantly computes the merge decision
// (~3 us of LDS/VALU preamble, L2-resident reads), then streams its slice
// of the one-hot output. Saves the separate 1-block merge dispatch + gap.
__global__ __launch_bounds__(256) void k_merge_write(const unsigned char* __restrict__ ids,
                                                     const float* __restrict__ sf,
                                                     const int* __restrict__ pl,
                                                     const int* __restrict__ pt,
                                                     const uint4* __restrict__ edge_blocks,
                                                     float* __restrict__ out) {
    __shared__ float sfn[28 * 65];          // stride-65 pad kills bank conflicts
    __shared__ unsigned step_word[512];     // ci | cj<<8 | hz<<16 | pass<<17
    __shared__ uint4 wred[4];
    __shared__ unsigned fedge[4];           // final l,r,t,b edge masks
    __shared__ int sP;
    __shared__ int loc[32];

    const int tid = threadIdx.x;
    const int lane = tid & 63;
    const int wave = tid >> 6;

    // 1) OR-reduce per-block edge masks (1024 x uint4, L2-hot)
    unsigned el = 0, er = 0, et = 0, eb = 0;
    for (int b = tid; b < NBLK; b += 256) {
        const uint4 w = edge_blocks[b];
        el |= w.x; er |= w.y; et |= w.z; eb |= w.w;
    }
#pragma unroll
    for (int off = 1; off < 64; off <<= 1) {
        el |= __shfl_xor(el, off);
        er |= __shfl_xor(er, off);
        et |= __shfl_xor(et, off);
        eb |= __shfl_xor(eb, off);
    }
    if (lane == 0) wred[wave] = make_uint4(el, er, et, eb);

    // 2) normalize slot features: row r handled by wave (r & 3)
#pragma unroll
    for (int i = 0; i < 7; i++) {
        const int r = wave + 4 * i;         // 0..27
        const float v = sf[r * 64 + lane];
        float s = v * v;
#pragma unroll
        for (int off = 1; off < 64; off <<= 1) s += __shfl_xor(s, off);
        sfn[r * 65 + lane] = v * (1.0f / (sqrtf(s) + 1e-8f));
    }
    __syncthreads();

    // 3) final edge masks + pair list in reference order (thread 0)
    if (tid == 0) {
        unsigned fl = wred[0].x | wred[1].x | wred[2].x | wred[3].x;
        unsigned fr = wred[0].y | wred[1].y | wred[2].y | wred[3].y;
        unsigned ft = wred[0].z | wred[1].z | wred[2].z | wred[3].z;
        unsigned fb = wred[0].w | wred[1].w | wred[2].w | wred[3].w;
        fedge[0] = fl; fedge[1] = fr; fedge[2] = ft; fedge[3] = fb;

        int lpl[4], lpt[4];
        for (int i = 0; i < 4; i++) { lpl[i] = pl[i]; lpt[i] = pt[i]; }
        int aI[8], aJ[8], aH[8], na = 0;
        for (int i = 0; i < N_WINDOWS; i++)
            for (int j = i + 1; j < N_WINDOWS; j++) {
                if (lpt[i] == lpt[j] && abs(lpl[i] - lpl[j]) == WIN_W) {
                    if (lpl[i] < lpl[j]) { aI[na] = i; aJ[na] = j; }
                    else                 { aI[na] = j; aJ[na] = i; }
                    aH[na] = 1; na++;
                }
                if (lpl[i] == lpl[j] && abs(lpt[i] - lpt[j]) == WIN_H) {
                    if (lpt[i] < lpt[j]) { aI[na] = i; aJ[na] = j; }
                    else                 { aI[na] = j; aJ[na] = i; }
                    aH[na] = 0; na++;
                }
            }
        int P = 0;
        for (int a = 0; a < na; a++)
            for (int ci = aI[a] * MPW + 1; ci < (aI[a] + 1) * MPW; ci++)
                for (int cj = aJ[a] * MPW + 1; cj < (aJ[a] + 1) * MPW; cj++)
                    step_word[P++] = (unsigned)ci | ((unsigned)cj << 8)
                                   | ((unsigned)aH[a] << 16);
        sP = P;
    }
    __syncthreads();

    // 4) sims + pass bit (one pair per thread)
    const int P = sP;
    {
        const unsigned ger = fedge[1], gel = fedge[0], geb = fedge[3], get = fedge[2];
        for (int p = tid; p < P; p += 256) {
            const unsigned w = step_word[p];
            const int ci = w & 255, cj = (w >> 8) & 255, hz = (w >> 16) & 1;
            const float* fi = &sfn[((ci >> 3) * (MPW - 1) + (ci & 7) - 1) * 65];
            const float* fj = &sfn[((cj >> 3) * (MPW - 1) + (cj & 7) - 1) * 65];
            float s = 0.f;
#pragma unroll
            for (int k = 0; k < 64; k++) s += fi[k] * fj[k];
            const bool eok = hz ? (((ger >> ci) & 1u) && ((gel >> cj) & 1u))
                                : (((geb >> ci) & 1u) && ((get >> cj) & 1u));
            if (eok && s > SIM_THRESH) step_word[p] = w | (1u << 17);
        }
    }
    __syncthreads();

    // 5) sequential scan (wave 0, lane c carries loc[c])
    if (wave == 0) {
        unsigned merged = 0;
        int myloc = lane;
        for (int p = 0; p < P; p++) {
            const unsigned w = step_word[p];        // LDS broadcast
            if (w >> 17) {
                const int ci = w & 255, cj = (w >> 8) & 255;
                if (!((merged >> ci) & 1u) && !((merged >> cj) & 1u)) {
                    const int keep = min(ci, cj), rem = max(ci, cj);
                    if (myloc == rem) myloc = keep;
                    merged |= 1u << rem;
                }
            }
        }
        if (lane < 32) loc[lane] = myloc;
    }
    __syncthreads();

    // 6) write one-hot output: 4 px/thread, nontemporal float4 stores
    const int idx = (blockIdx.x * 256 + tid) * 4;   // exact fit
    const uchar4 id4 = *(const uchar4*)(ids + idx);
    const int r0 = loc[id4.x], r1 = loc[id4.y], r2 = loc[id4.z], r3 = loc[id4.w];
#pragma unroll
    for (int c = 0; c < N_MASKS; c++) {
        vf4 v;
        v.x = (r0 == c) ? 1.0f : 0.0f;
        v.y = (r1 == c) ? 1.0f : 0.0f;
        v.z = (r2 == c) ? 1.0f : 0.0f;
        v.w = (r3 == c) ? 1.0f : 0.0f;
        __builtin_nontemporal_store(v, (vf4*)(out + (size_t)c * NPIX + idx));
    }
}

extern "C" void kernel_launch(void* const* d_in, const int* in_sizes, int n_in,
                              void* d_out, int out_size, void* d_ws, size_t ws_size,
                              hipStream_t stream) {
    const float* masks = (const float*)d_in[0];   // (1, 32, 1024, 1024) f32
    const float* sf    = (const float*)d_in[1];   // (4, 7, 64) f32
    const int*   pl    = (const int*)d_in[2];     // (4,) i32
    const int*   pt    = (const int*)d_in[3];     // (4,) i32
    float* out = (float*)d_out;

    char* ws = (char*)d_ws;
    uint4* edge_blocks = (uint4*)(ws + WS_EDGE);
    unsigned char* ids = (unsigned char*)(ws + WS_IDS);

    k_argmax<<<NBLK, 256, 0, stream>>>(masks, pl, pt, edge_blocks, ids);
    k_merge_write<<<NBLK, 256, 0, stream>>>(ids, sf, pl, pt, edge_blocks, out);
}